// Round 19
// baseline (236.916 us; speedup 1.0000x reference)
//
#include <hip/hip_runtime.h>
#include <hip/hip_bf16.h>
#include <cstddef>

#define SEQ 2048
#define DM  512
#define DI  1024   // d_inner
#define DR  32     // dt_rank
#define DS  64     // d_state
#define NCHUNK 32
#define CHUNK  64  // SEQ / NCHUNK
#define MB (1024 * 1024)
#define NCVT 1664  // (1048576 + 131072 + 524288) / 1024

typedef __attribute__((ext_vector_type(4))) float f32x4;
typedef __attribute__((ext_vector_type(8))) short frag8;

// round-to-nearest-even f32 -> bf16 raw bits (finite inputs)
__device__ __forceinline__ unsigned short f2bf(float f) {
    unsigned u = __float_as_uint(f);
    unsigned r = (u + 0x7fffu + ((u >> 16) & 1u)) >> 16;
    return (unsigned short)r;
}
__device__ __forceinline__ float bf2f(unsigned short u) {
    return __int_as_float(((int)u) << 16);
}

// hardware exp2 (v_exp_f32)
__device__ __forceinline__ float fexp2(float x) {
#if __has_builtin(__builtin_amdgcn_exp2f)
    return __builtin_amdgcn_exp2f(x);
#else
    return exp2f(x);
#endif
}
#define LOG2E 1.44269504088896f

// p + dpp_permute(p), compile-time DPP control
template <int CTRL>
__device__ __forceinline__ float dppadd(float p) {
    return p + __int_as_float(
        __builtin_amdgcn_update_dpp(0, __float_as_int(p), CTRL, 0xF, 0xF, true));
}

// ---------------- Wfused = Wdt @ Wx[0:32]  -> bf16 rows 128.. of WxBC ------
// C[e][k] = sum_r Wdt[e][r] * Wx[r][k].  Grid (DI/64, DI/64), 256 thr.
__global__ void wfused_kernel(const float* __restrict__ Wdt, const float* __restrict__ Wx,
                              unsigned short* __restrict__ WxBC) {
    __shared__ float As[DR][65];  // [r][e_local]
    __shared__ float Bs[DR][65];  // [r][k_local]
    int t = threadIdx.x;
    int e0 = blockIdx.x * 64, k0 = blockIdx.y * 64;
    for (int c = t; c < 512; c += 256) {         // Wdt tile 64x32
        int er = c >> 3, r4 = (c & 7) * 4;
        float4 v = *(const float4*)(Wdt + (size_t)(e0 + er) * DR + r4);
        As[r4][er] = v.x; As[r4 + 1][er] = v.y; As[r4 + 2][er] = v.z; As[r4 + 3][er] = v.w;
    }
    for (int c = t; c < 512; c += 256) {         // Wx tile 32x64
        int rr = c >> 4, k4 = (c & 15) * 4;
        float4 v = *(const float4*)(Wx + (size_t)rr * DI + k0 + k4);
        Bs[rr][k4] = v.x; Bs[rr][k4 + 1] = v.y; Bs[rr][k4 + 2] = v.z; Bs[rr][k4 + 3] = v.w;
    }
    __syncthreads();
    int tx = t & 15, ty = t >> 4;
    float acc[4][4] = {};
#pragma unroll
    for (int r = 0; r < DR; r++) {
        float a[4], b[4];
#pragma unroll
        for (int i = 0; i < 4; i++) a[i] = As[r][ty * 4 + i];
#pragma unroll
        for (int j = 0; j < 4; j++) b[j] = Bs[r][tx * 4 + j];
#pragma unroll
        for (int i = 0; i < 4; i++)
#pragma unroll
            for (int j = 0; j < 4; j++)
                acc[i][j] = fmaf(a[i], b[j], acc[i][j]);
    }
#pragma unroll
    for (int i = 0; i < 4; i++) {
        ushort4 o = { f2bf(acc[i][0]), f2bf(acc[i][1]), f2bf(acc[i][2]), f2bf(acc[i][3]) };
        *(ushort4*)(WxBC + (size_t)(128 + e0 + ty * 4 + i) * DI + k0 + tx * 4) = o;
    }
}

// ---------------- fused: weights->bf16 (blocks < NCVT) + LayerNorm --------
// Win 1,048,576 -> Win_bf; Wx rows 32..160 (131,072) -> WxBC rows 0..127;
// Wout 524,288 -> Wout_bf.
__global__ void cvt_ln(const float* __restrict__ w1, unsigned short* __restrict__ o1,
                       const float* __restrict__ w2, unsigned short* __restrict__ o2,
                       const float* __restrict__ w3, unsigned short* __restrict__ o3,
                       const float* __restrict__ x, const float* __restrict__ g,
                       const float* __restrict__ b, unsigned short* __restrict__ xn) {
    if (blockIdx.x < NCVT) {
        const int n1 = 1048576, n2 = 131072, n3 = 524288;
        int i = (blockIdx.x * 256 + threadIdx.x) * 4;
        const float* s; unsigned short* d; int off;
        if (i < n1) { s = w1; d = o1; off = i; }
        else if (i < n1 + n2) { s = w2; d = o2; off = i - n1; }
        else if (i < n1 + n2 + n3) { s = w3; d = o3; off = i - n1 - n2; }
        else return;
        float4 v = *(const float4*)(s + off);
        ushort4 o = { f2bf(v.x), f2bf(v.y), f2bf(v.z), f2bf(v.w) };
        *(ushort4*)(d + off) = o;
        return;
    }
    int l = blockIdx.x - NCVT;
    int t = threadIdx.x;
    __shared__ float red[256];
    float v0 = x[l * DM + t];
    float v1 = x[l * DM + t + 256];
    red[t] = v0 + v1;
    __syncthreads();
    for (int o = 128; o > 0; o >>= 1) { if (t < o) red[t] += red[t + o]; __syncthreads(); }
    float mu = red[0] * (1.f / DM);
    __syncthreads();
    float c0 = v0 - mu, c1 = v1 - mu;
    red[t] = c0 * c0 + c1 * c1;
    __syncthreads();
    for (int o = 128; o > 0; o >>= 1) { if (t < o) red[t] += red[t + o]; __syncthreads(); }
    float rstd = rsqrtf(red[0] * (1.f / DM) + 1e-5f);
    xn[l * DM + t]       = f2bf(c0 * rstd * g[t]       + b[t]);
    xn[l * DM + t + 256] = f2bf(c1 * rstd * g[t + 256] + b[t + 256]);
}

#define LDK 40

// ---------------- 128x64 bf16 MFMA GEMM ------------------------------------
// EPI 1: in-proj split (N=2048): n<DI -> bf16 outB1 [M][DI]; n>=DI -> silu ->
//        bf16 transposed outB2 [DI][SEQ].
// EPI 2: fp32 + residual -> outF.
// EPI 5: x-proj+dt fused (N=1152): n<64 -> bf16 B at bci[m][2n];
//        64<=n<128 -> bf16 C at bci[m][2(n-64)+1]; n>=128 -> e=n-128,
//        softplus(acc + res[e]) -> fp32 transposed outF[e*SEQ + m] (float4).
template <int EPI>
__global__ __launch_bounds__(256, 2)
void gemm_bf(const unsigned short* __restrict__ A, int lda,
             const unsigned short* __restrict__ B, int ldb,
             int N, int K,
             float* __restrict__ outF, const float* __restrict__ res, int ldo,
             unsigned short* __restrict__ bci,
             unsigned short* __restrict__ outB1, unsigned short* __restrict__ outB2) {
    __shared__ unsigned short As[128 * LDK];
    __shared__ unsigned short Bs[64 * LDK];
    int t = threadIdx.x;
    int lane = t & 63;
    int wv = t >> 6;
    int wm = (wv >> 1) * 64;
    int wn = (wv & 1) * 32;
    int m0 = blockIdx.x * 128, n0 = blockIdx.y * 64;

    f32x4 acc[4][2];
#pragma unroll
    for (int i = 0; i < 4; i++)
#pragma unroll
        for (int j = 0; j < 2; j++) acc[i][j] = (f32x4){0.f, 0.f, 0.f, 0.f};

    int lm = lane & 15;
    int kq = (lane >> 4) * 8;

    for (int k0 = 0; k0 < K; k0 += 32) {
#pragma unroll
        for (int j = 0; j < 2; j++) {
            int c = t + j * 256;
            int m = c >> 2;
            int k = (c & 3) * 8;
            frag8 v = *(const frag8*)(A + (size_t)(m0 + m) * lda + k0 + k);
            *(frag8*)(&As[m * LDK + k]) = v;
        }
        {
            int m = t >> 2;
            int k = (t & 3) * 8;
            int gn = n0 + m;
            frag8 v = {0, 0, 0, 0, 0, 0, 0, 0};
            if (gn < N) v = *(const frag8*)(B + (size_t)gn * ldb + k0 + k);
            *(frag8*)(&Bs[m * LDK + k]) = v;
        }
        __syncthreads();

        frag8 af[4], bfr[2];
#pragma unroll
        for (int mt = 0; mt < 4; mt++)
            af[mt] = *(const frag8*)(&As[(wm + mt * 16 + lm) * LDK + kq]);
#pragma unroll
        for (int nt = 0; nt < 2; nt++)
            bfr[nt] = *(const frag8*)(&Bs[(wn + nt * 16 + lm) * LDK + kq]);
#pragma unroll
        for (int mt = 0; mt < 4; mt++)
#pragma unroll
            for (int nt = 0; nt < 2; nt++)
                acc[mt][nt] = __builtin_amdgcn_mfma_f32_16x16x32_bf16(
                    af[mt], bfr[nt], acc[mt][nt], 0, 0, 0);
        __syncthreads();
    }

    int rbase = (lane >> 4) * 4;
#pragma unroll
    for (int mt = 0; mt < 4; mt++) {
#pragma unroll
        for (int nt = 0; nt < 2; nt++) {
            int n = n0 + wn + nt * 16 + lm;
            int mb = m0 + wm + mt * 16 + rbase;
            if (EPI == 1) {
                if (n < DI) {
#pragma unroll
                    for (int r = 0; r < 4; r++)
                        outB1[(size_t)(mb + r) * DI + n] = f2bf(acc[mt][nt][r]);
                } else {
                    int nn = n - DI;
                    ushort4 o;
#pragma unroll
                    for (int r = 0; r < 4; r++) {
                        float v = acc[mt][nt][r];
                        v = v / (1.f + __expf(-v));
                        (&o.x)[r] = f2bf(v);
                    }
                    *(ushort4*)(outB2 + (size_t)nn * SEQ + mb) = o;
                }
            } else if (EPI == 2) {
                if (n < N) {
#pragma unroll
                    for (int r = 0; r < 4; r++)
                        outF[(size_t)(mb + r) * ldo + n] =
                            acc[mt][nt][r] + res[(size_t)(mb + r) * ldo + n];
                }
            } else { // EPI == 5
                if (n < 64) {
                    int col = 2 * n;
#pragma unroll
                    for (int r = 0; r < 4; r++)
                        bci[(size_t)(mb + r) * 128 + col] = f2bf(acc[mt][nt][r]);
                } else if (n < 128) {
                    int col = 2 * (n - 64) + 1;
#pragma unroll
                    for (int r = 0; r < 4; r++)
                        bci[(size_t)(mb + r) * 128 + col] = f2bf(acc[mt][nt][r]);
                } else {
                    int e = n - 128;
                    float bv = res[e];
                    float4 o;
#pragma unroll
                    for (int r = 0; r < 4; r++) {
                        float v = acc[mt][nt][r] + bv;
                        v = (v > 20.f) ? v : __logf(1.f + __expf(v));
                        (&o.x)[r] = v;
                    }
                    *(float4*)(outF + (size_t)e * SEQ + mb) = o;
                }
            }
        }
    }
}

// ---------------- fused conv(w=4, causal) + bias + SiLU + transpose -------
__global__ void conv_t(const unsigned short* __restrict__ xi_raw,
                       const float* __restrict__ w, const float* __restrict__ cb,
                       unsigned short* __restrict__ xi2bf, unsigned short* __restrict__ xi2T) {
    __shared__ float tin[67][72];
    __shared__ float tout[64][65];
    int l0 = blockIdx.x * 64, e0 = blockIdx.y * 64;
    int t = threadIdx.x;
    for (int c = t; c < 536; c += 256) {      // 67 rows x 8 chunks of 8
        int r = c >> 3, ke = (c & 7) * 8;
        int l = l0 - 3 + r;
        frag8 v = {0, 0, 0, 0, 0, 0, 0, 0};
        if (l >= 0) v = *(const frag8*)(xi_raw + (size_t)l * DI + e0 + ke);
#pragma unroll
        for (int i = 0; i < 8; i++) tin[r][ke + i] = bf2f((unsigned short)v[i]);
    }
    __syncthreads();
    int e_loc = t & 63;
    int e = e0 + e_loc;
    float4 wv = *(const float4*)(w + e * 4);
    float bias = cb[e];
#pragma unroll 4
    for (int i = 0; i < 16; i++) {
        int l_loc = (t >> 6) + i * 4;
        float acc = bias;
        acc = fmaf(wv.x, tin[l_loc][e_loc], acc);
        acc = fmaf(wv.y, tin[l_loc + 1][e_loc], acc);
        acc = fmaf(wv.z, tin[l_loc + 2][e_loc], acc);
        acc = fmaf(wv.w, tin[l_loc + 3][e_loc], acc);
        float s = acc / (1.f + __expf(-acc));
        tout[l_loc][e_loc] = s;
        xi2bf[(size_t)(l0 + l_loc) * DI + e] = f2bf(s);
    }
    __syncthreads();
    for (int c = t; c < 1024; c += 256) {     // 64 e-rows x 16 l-chunks of 4
        int er = c >> 4, l4 = (c & 15) * 4;
        ushort4 o = { f2bf(tout[l4][er]), f2bf(tout[l4 + 1][er]),
                      f2bf(tout[l4 + 2][er]), f2bf(tout[l4 + 3][er]) };
        *(ushort4*)(xi2T + (size_t)(e0 + er) * SEQ + l0 + l4) = o;
    }
}

// ---------------- Chunked selective scan: 4 states/lane x 4 channels/wave --
// Lane (g=lane>>4, i=lane&15) holds states 4i..4i+3 of channel e0+g.
// NCHUNK=32 (8 waves/SIMD). passA emits per-channel sum_d + fp32 hend; carry
// recomputes P=exp2(Ae2*sum_d) and writes h_in in-place over hend.
__global__ void scan_passA(const float* __restrict__ deltaT, const unsigned short* __restrict__ xi2T,
                           const unsigned short* __restrict__ bci, const float* __restrict__ A_log,
                           float* __restrict__ sumd, float* __restrict__ hend) {
    int wid = blockIdx.x * 4 + (threadIdx.x >> 6);
    int eg = wid & 255;        // channel group (DI/4)
    int c  = wid >> 8;         // chunk 0..NCHUNK-2
    int lane = threadIdx.x & 63;
    int g = lane >> 4;         // channel within group
    int i = lane & 15;         // state quad
    int e = eg * 4 + g;
    int l0 = c * CHUNK;
    float4 al = *(const float4*)(A_log + e * DS + 4 * i);
    float Ae2[4];
#pragma unroll
    for (int k = 0; k < 4; k++) Ae2[k] = -__expf((&al.x)[k]) * LOG2E;
    float h[4] = {0.f, 0.f, 0.f, 0.f};
    float sum_d = 0.f;
    const float4* d4  = (const float4*)(deltaT + (size_t)e * SEQ + l0);
    const ushort4* x4 = (const ushort4*)(xi2T + (size_t)e * SEQ + l0);
    const uint4* bc4  = (const uint4*)((const unsigned*)bci + (size_t)l0 * 64) + i;
    for (int gq = 0; gq < CHUNK / 4; gq++) {
        float4 dd = d4[gq];
        ushort4 xx = x4[gq];
#pragma unroll
        for (int j = 0; j < 4; j++) {
            uint4 bcv = bc4[(4 * gq + j) * 16];
            float dj = (&dd.x)[j];
            float dx = dj * bf2f((&xx.x)[j]);
            sum_d += dj;
#pragma unroll
            for (int k = 0; k < 4; k++) {
                float dA = fexp2(dj * Ae2[k]);
                float Bk = __int_as_float((&bcv.x)[k] << 16);
                h[k] = fmaf(dA, h[k], dx * Bk);
            }
        }
    }
    size_t idx = ((size_t)c * DI + e) * DS + 4 * i;
    float4 hv = {h[0], h[1], h[2], h[3]};
    *(float4*)(hend + idx) = hv;
    if (i == 0) sumd[c * DI + e] = sum_d;
}

// Carry: batched loads (all chunks up front, independent) then register
// chain; h_in written over hend in-place. Last slot write-only.
__global__ void scan_carry(float* __restrict__ hend, const float* __restrict__ sumd,
                           const float* __restrict__ A_log) {
    int e = blockIdx.x * 4 + (threadIdx.x >> 6);
    int n = threadIdx.x & 63;
    float Ae2 = -__expf(A_log[e * DS + n]) * LOG2E;
    float he[NCHUNK - 1], sd[NCHUNK - 1];
#pragma unroll
    for (int c = 0; c < NCHUNK - 1; c++)
        he[c] = hend[((size_t)c * DI + e) * DS + n];
#pragma unroll
    for (int c = 0; c < NCHUNK - 1; c++)
        sd[c] = sumd[c * DI + e];
    float h = 0.f;
#pragma unroll
    for (int c = 0; c < NCHUNK - 1; c++) {
        float P = fexp2(Ae2 * sd[c]);
        hend[((size_t)c * DI + e) * DS + n] = h;
        h = fmaf(P, h, he[c]);
    }
    hend[((size_t)(NCHUNK - 1) * DI + e) * DS + n] = h;
}

// Pass B: local 4-state fma chain + 4-DPP 16-lane row reduce; lane i==0 of
// each row gates with silu(z) (szT read-only) and stores y directly to
// y_bf [SEQ][DI].
__global__ void scan_passB(const float* __restrict__ deltaT, const unsigned short* __restrict__ xi2T,
                           const unsigned short* __restrict__ bci, const unsigned short* __restrict__ szT,
                           const float* __restrict__ A_log, const float* __restrict__ Dp,
                           const float* __restrict__ hin, unsigned short* __restrict__ y_bf) {
    int wid = blockIdx.x * 4 + (threadIdx.x >> 6);
    int eg = wid & 255;
    int c  = wid >> 8;
    int lane = threadIdx.x & 63;
    int g = lane >> 4;
    int i = lane & 15;
    int e = eg * 4 + g;
    int l0 = c * CHUNK;
    float4 al = *(const float4*)(A_log + e * DS + 4 * i);
    float Ae2[4];
#pragma unroll
    for (int k = 0; k < 4; k++) Ae2[k] = -__expf((&al.x)[k]) * LOG2E;
    float dp = Dp[e];
    float4 hv = *(const float4*)(hin + ((size_t)c * DI + e) * DS + 4 * i);
    float h[4] = {hv.x, hv.y, hv.z, hv.w};
    const float4* d4  = (const float4*)(deltaT + (size_t)e * SEQ + l0);
    const ushort4* x4 = (const ushort4*)(xi2T + (size_t)e * SEQ + l0);
    const ushort4* s4 = (const ushort4*)(szT + (size_t)e * SEQ + l0);
    const uint4* bc4  = (const uint4*)((const unsigned*)bci + (size_t)l0 * 64) + i;
    for (int gq = 0; gq < CHUNK / 4; gq++) {
        float4 dd = d4[gq];
        ushort4 xx = x4[gq], zz = s4[gq];
        ushort4 yv;
#pragma unroll
        for (int j = 0; j < 4; j++) {
            uint4 bcv = bc4[(4 * gq + j) * 16];
            float dj = (&dd.x)[j];
            float xj = bf2f((&xx.x)[j]);
            float dx = dj * xj;
            float Ck[4];
#pragma unroll
            for (int k = 0; k < 4; k++) {
                unsigned w = (&bcv.x)[k];
                float Bk = __int_as_float(w << 16);
                Ck[k] = __int_as_float(w & 0xffff0000u);
                float dA = fexp2(dj * Ae2[k]);
                h[k] = fmaf(dA, h[k], dx * Bk);
            }
            float p = h[0] * Ck[0];
            p = fmaf(h[1], Ck[1], p);
            p = fmaf(h[2], Ck[2], p);
            p = fmaf(h[3], Ck[3], p);
            p = dppadd<0xB1>(p);   // quad_perm swap-1
            p = dppadd<0x4E>(p);   // quad_perm swap-2
            p = dppadd<0x141>(p);  // row_half_mirror
            p = dppadd<0x140>(p);  // row_mirror -> 16-lane row sum (all lanes)
            (&yv.x)[j] = f2bf((p + dp * xj) * bf2f((&zz.x)[j]));
        }
        if (i == 0) {
#pragma unroll
            for (int j = 0; j < 4; j++)
                y_bf[(size_t)(l0 + 4 * gq + j) * DI + e] = (&yv.x)[j];
        }
    }
}

extern "C" void kernel_launch(void* const* d_in, const int* in_sizes, int n_in,
                              void* d_out, int out_size, void* d_ws, size_t ws_size,
                              hipStream_t stream) {
    const float* x      = (const float*)d_in[0];
    const float* ln_g   = (const float*)d_in[1];
    const float* ln_b   = (const float*)d_in[2];
    const float* Win    = (const float*)d_in[3];
    const float* conv_w = (const float*)d_in[4];
    const float* conv_b = (const float*)d_in[5];
    const float* Wx     = (const float*)d_in[6];
    const float* Wdt    = (const float*)d_in[7];
    const float* bdt    = (const float*)d_in[8];
    const float* A_log  = (const float*)d_in[9];
    const float* Dp     = (const float*)d_in[10];
    const float* Wout   = (const float*)d_in[11];
    float* out = (float*)d_out;

    // Workspace map (29.6 MB peak; 31.5 MB proven safe). Lifetimes:
    //  0- 8: xi_raw (2-3) -> deltaT (4-8)
    //  8-12: Win_bf (1-2) -> xi2bf (3-4) -> y_bf (8-9)
    // 12-16: szT (2-8, read-only in passB)
    // 16-20: xi2T (3-8)
    // 20-22: xn_bf (1-2) -> hend[0:2MB) (6-8)
    // 22-24.25: WxBC [1152][DI] bf16 (0-4) -> hend[2:4.25MB) (6-8)
    // 20-28: hend fp32 [NCHUNK][DI][DS] (6-8)
    // 28-29: Wout_bf (1-9); 29+: sumd 128K | bci 512K
    char* W = (char*)d_ws;
    unsigned short* xi_raw  = (unsigned short*)W;
    float*          deltaT  = (float*)W;
    unsigned short* Win_bf  = (unsigned short*)(W + 8 * MB);
    unsigned short* xi2bf   = (unsigned short*)(W + 8 * MB);
    unsigned short* y_bf    = (unsigned short*)(W + 8 * MB);
    unsigned short* szT     = (unsigned short*)(W + 12 * MB);
    unsigned short* xi2T    = (unsigned short*)(W + 16 * MB);
    unsigned short* xn_bf   = (unsigned short*)(W + 20 * MB);
    unsigned short* WxBC    = (unsigned short*)(W + 22 * MB);  // 1152 x 1024 bf16
    float*          hend    = (float*)(W + 20 * MB);
    unsigned short* Wout_bf = (unsigned short*)(W + 28 * MB);
    float*          sumd    = (float*)(W + 29 * MB);
    unsigned short* bci     = (unsigned short*)(W + 29 * MB + 128 * 1024);

    // 0. Wfused = Wdt @ Wx[0:32] -> WxBC rows 128..1151 (weights only)
    wfused_kernel<<<dim3(DI / 64, DI / 64), 256, 0, stream>>>(Wdt, Wx, WxBC);

    // 1. fused: weights -> bf16 (Win; Wx rows 32..160 -> WxBC rows 0..127;
    //    Wout) + LayerNorm
    cvt_ln<<<NCVT + SEQ, 256, 0, stream>>>(Win, Win_bf, Wx + 32 * DI, WxBC,
                                           Wout, Wout_bf, x, ln_g, ln_b, xn_bf);

    // 2. fused in-proj [2048 x 2048 x 512]: lower half -> xi_raw bf16,
    //    upper half -> silu -> szT bf16 transposed
    gemm_bf<1><<<dim3(SEQ / 128, 2048 / 64), 256, 0, stream>>>(
        xn_bf, DM, Win_bf, DM, 2048, DM, nullptr, nullptr, 0, nullptr,
        xi_raw, szT);

    // 3. fused conv + SiLU + transpose -> xi2bf [SEQ][DI] + xi2T [DI][SEQ]
    conv_t<<<dim3(SEQ / 64, DI / 64), 256, 0, stream>>>(xi_raw, conv_w, conv_b, xi2bf, xi2T);

    // 4. fused x-proj + dt-proj (N=1152): B/C -> bci; delta -> softplus ->
    //    deltaT [DI][SEQ] fp32 transposed (bias = bdt)
    gemm_bf<5><<<dim3(SEQ / 128, 1152 / 64), 256, 0, stream>>>(
        xi2bf, DI, WxBC, DI, 1152, DI, deltaT, bdt, 0, bci, nullptr, nullptr);

    // 5. chunked scan (4 ch/wave, 32 chunks): A (0..30) -> carry -> B
    scan_passA<<<(DI / 4) * (NCHUNK - 1) / 4, 256, 0, stream>>>(deltaT, xi2T, bci, A_log, sumd, hend);
    scan_carry<<<DI / 4, 256, 0, stream>>>(hend, sumd, A_log);
    scan_passB<<<(DI / 4) * NCHUNK / 4, 256, 0, stream>>>(deltaT, xi2T, bci, szT,
                                                          A_log, Dp, hend, y_bf);

    // 6. out = y @ Wout^T + x  fp32  (y_bf written directly by passB)
    gemm_bf<2><<<dim3(SEQ / 128, DM / 64), 256, 0, stream>>>(
        y_bf, DI, Wout_bf, DI, DM, DI, out, x, DM, nullptr, nullptr, nullptr);
}

// Round 20
// 235.123 us; speedup vs baseline: 1.0076x; 1.0076x over previous
//
#include <hip/hip_runtime.h>
#include <hip/hip_bf16.h>
#include <cstddef>

#define SEQ 2048
#define DM  512
#define DI  1024   // d_inner
#define DR  32     // dt_rank
#define DS  64     // d_state
#define NCHUNK 32
#define CHUNK  64  // SEQ / NCHUNK
#define MB (1024 * 1024)
#define NCVT 1696  // blocks for weight conversion part of cvt_ln

typedef __attribute__((ext_vector_type(4))) float f32x4;
typedef __attribute__((ext_vector_type(8))) short frag8;

// round-to-nearest-even f32 -> bf16 raw bits (finite inputs)
__device__ __forceinline__ unsigned short f2bf(float f) {
    unsigned u = __float_as_uint(f);
    unsigned r = (u + 0x7fffu + ((u >> 16) & 1u)) >> 16;
    return (unsigned short)r;
}
__device__ __forceinline__ float bf2f(unsigned short u) {
    return __int_as_float(((int)u) << 16);
}

// hardware exp2 (v_exp_f32)
__device__ __forceinline__ float fexp2(float x) {
#if __has_builtin(__builtin_amdgcn_exp2f)
    return __builtin_amdgcn_exp2f(x);
#else
    return exp2f(x);
#endif
}
#define LOG2E 1.44269504088896f

// p + dpp_permute(p), compile-time DPP control
template <int CTRL>
__device__ __forceinline__ float dppadd(float p) {
    return p + __int_as_float(
        __builtin_amdgcn_update_dpp(0, __float_as_int(p), CTRL, 0xF, 0xF, true));
}

// ---------------- fused: weights->bf16 (blocks < NCVT) + LayerNorm --------
// Sizes: Win 1,048,576; Wx 163,840; Wout 524,288 -> total 1,736,704 = NCVT*1024.
__global__ void cvt_ln(const float* __restrict__ w1, unsigned short* __restrict__ o1,
                       const float* __restrict__ w2, unsigned short* __restrict__ o2,
                       const float* __restrict__ w3, unsigned short* __restrict__ o3,
                       const float* __restrict__ x, const float* __restrict__ g,
                       const float* __restrict__ b, unsigned short* __restrict__ xn) {
    if (blockIdx.x < NCVT) {
        const int n1 = 1048576, n2 = 163840, n3 = 524288;
        int i = (blockIdx.x * 256 + threadIdx.x) * 4;
        const float* s; unsigned short* d; int off;
        if (i < n1) { s = w1; d = o1; off = i; }
        else if (i < n1 + n2) { s = w2; d = o2; off = i - n1; }
        else if (i < n1 + n2 + n3) { s = w3; d = o3; off = i - n1 - n2; }
        else return;
        float4 v = *(const float4*)(s + off);
        ushort4 o = { f2bf(v.x), f2bf(v.y), f2bf(v.z), f2bf(v.w) };
        *(ushort4*)(d + off) = o;
        return;
    }
    int l = blockIdx.x - NCVT;
    int t = threadIdx.x;
    __shared__ float red[256];
    float v0 = x[l * DM + t];
    float v1 = x[l * DM + t + 256];
    red[t] = v0 + v1;
    __syncthreads();
    for (int o = 128; o > 0; o >>= 1) { if (t < o) red[t] += red[t + o]; __syncthreads(); }
    float mu = red[0] * (1.f / DM);
    __syncthreads();
    float c0 = v0 - mu, c1 = v1 - mu;
    red[t] = c0 * c0 + c1 * c1;
    __syncthreads();
    for (int o = 128; o > 0; o >>= 1) { if (t < o) red[t] += red[t + o]; __syncthreads(); }
    float rstd = rsqrtf(red[0] * (1.f / DM) + 1e-5f);
    xn[l * DM + t]       = f2bf(c0 * rstd * g[t]       + b[t]);
    xn[l * DM + t + 256] = f2bf(c1 * rstd * g[t + 256] + b[t + 256]);
}

#define LDK 40

// ---------------- 128x64 bf16 MFMA GEMM ------------------------------------
// EPI 1: in-proj split (N=2048): n<DI -> bf16 outB1 [M][DI]; n>=DI -> silu ->
//        bf16 transposed outB2 [DI][SEQ].
// EPI 2: fp32 + residual -> outF.
// EPI 4: x-proj split: n<32 -> fp32 dtc [SEQ][32]; 32<=n<96 -> bf16 B at
//        bci[m][2(n-32)]; 96<=n<160 -> bf16 C at bci[m][2(n-96)+1].
template <int EPI>
__global__ __launch_bounds__(256, 2)
void gemm_bf(const unsigned short* __restrict__ A, int lda,
             const unsigned short* __restrict__ B, int ldb,
             int N, int K,
             float* __restrict__ outF, const float* __restrict__ res, int ldo,
             float* __restrict__ dtc, unsigned short* __restrict__ bci,
             unsigned short* __restrict__ outB1, unsigned short* __restrict__ outB2) {
    __shared__ unsigned short As[128 * LDK];
    __shared__ unsigned short Bs[64 * LDK];
    int t = threadIdx.x;
    int lane = t & 63;
    int wv = t >> 6;
    int wm = (wv >> 1) * 64;
    int wn = (wv & 1) * 32;
    int m0 = blockIdx.x * 128, n0 = blockIdx.y * 64;

    f32x4 acc[4][2];
#pragma unroll
    for (int i = 0; i < 4; i++)
#pragma unroll
        for (int j = 0; j < 2; j++) acc[i][j] = (f32x4){0.f, 0.f, 0.f, 0.f};

    int lm = lane & 15;
    int kq = (lane >> 4) * 8;

    for (int k0 = 0; k0 < K; k0 += 32) {
#pragma unroll
        for (int j = 0; j < 2; j++) {
            int c = t + j * 256;
            int m = c >> 2;
            int k = (c & 3) * 8;
            frag8 v = *(const frag8*)(A + (size_t)(m0 + m) * lda + k0 + k);
            *(frag8*)(&As[m * LDK + k]) = v;
        }
        {
            int m = t >> 2;
            int k = (t & 3) * 8;
            int gn = n0 + m;
            frag8 v = {0, 0, 0, 0, 0, 0, 0, 0};
            if (gn < N) v = *(const frag8*)(B + (size_t)gn * ldb + k0 + k);
            *(frag8*)(&Bs[m * LDK + k]) = v;
        }
        __syncthreads();

        frag8 af[4], bfr[2];
#pragma unroll
        for (int mt = 0; mt < 4; mt++)
            af[mt] = *(const frag8*)(&As[(wm + mt * 16 + lm) * LDK + kq]);
#pragma unroll
        for (int nt = 0; nt < 2; nt++)
            bfr[nt] = *(const frag8*)(&Bs[(wn + nt * 16 + lm) * LDK + kq]);
#pragma unroll
        for (int mt = 0; mt < 4; mt++)
#pragma unroll
            for (int nt = 0; nt < 2; nt++)
                acc[mt][nt] = __builtin_amdgcn_mfma_f32_16x16x32_bf16(
                    af[mt], bfr[nt], acc[mt][nt], 0, 0, 0);
        __syncthreads();
    }

    int rbase = (lane >> 4) * 4;
#pragma unroll
    for (int mt = 0; mt < 4; mt++) {
#pragma unroll
        for (int nt = 0; nt < 2; nt++) {
            int n = n0 + wn + nt * 16 + lm;
            int mb = m0 + wm + mt * 16 + rbase;
            if (EPI == 1) {
                if (n < DI) {
#pragma unroll
                    for (int r = 0; r < 4; r++)
                        outB1[(size_t)(mb + r) * DI + n] = f2bf(acc[mt][nt][r]);
                } else {
                    int nn = n - DI;
                    ushort4 o;
#pragma unroll
                    for (int r = 0; r < 4; r++) {
                        float v = acc[mt][nt][r];
                        v = v / (1.f + __expf(-v));
                        (&o.x)[r] = f2bf(v);
                    }
                    *(ushort4*)(outB2 + (size_t)nn * SEQ + mb) = o;
                }
            } else if (EPI == 2) {
                if (n < N) {
#pragma unroll
                    for (int r = 0; r < 4; r++)
                        outF[(size_t)(mb + r) * ldo + n] =
                            acc[mt][nt][r] + res[(size_t)(mb + r) * ldo + n];
                }
            } else { // EPI == 4
                if (n < 32) {
#pragma unroll
                    for (int r = 0; r < 4; r++)
                        dtc[(size_t)(mb + r) * 32 + n] = acc[mt][nt][r];
                } else if (n < 96) {
                    int col = 2 * (n - 32);
#pragma unroll
                    for (int r = 0; r < 4; r++)
                        bci[(size_t)(mb + r) * 128 + col] = f2bf(acc[mt][nt][r]);
                } else if (n < 160) {
                    int col = 2 * (n - 96) + 1;
#pragma unroll
                    for (int r = 0; r < 4; r++)
                        bci[(size_t)(mb + r) * 128 + col] = f2bf(acc[mt][nt][r]);
                }
            }
        }
    }
}

// ---------------- dt-proj vector GEMM, transposed store (fp32) ------------
__global__ void gemm_dt_t(const float* __restrict__ A,   // dtc [SEQ][32]
                          const float* __restrict__ B,   // Wdt [DI][DR]
                          const float* __restrict__ bias,
                          float* __restrict__ outT) {    // deltaT [DI][SEQ]
    __shared__ float As[16][65];
    __shared__ float Bs[16][65];
    int tid = threadIdx.x;
    int tx = tid & 15, ty = tid >> 4;
    int bm = blockIdx.x * 64, bn = blockIdx.y * 64;   // bm: l, bn: e
    float acc[4][4] = {};
    int kk = tid & 15;
    int rr = tid >> 4;
    for (int k0 = 0; k0 < DR; k0 += 16) {
#pragma unroll
        for (int i = 0; i < 4; i++)
            As[kk][rr + 16 * i] = A[(size_t)(bm + rr + 16 * i) * 32 + k0 + kk];
#pragma unroll
        for (int i = 0; i < 4; i++)
            Bs[kk][rr + 16 * i] = B[(size_t)(bn + rr + 16 * i) * DR + k0 + kk];
        __syncthreads();
#pragma unroll
        for (int k = 0; k < 16; k++) {
            float a[4], bb[4];
#pragma unroll
            for (int i = 0; i < 4; i++) a[i] = As[k][ty * 4 + i];
#pragma unroll
            for (int j = 0; j < 4; j++) bb[j] = Bs[k][tx * 4 + j];
#pragma unroll
            for (int i = 0; i < 4; i++)
#pragma unroll
                for (int j = 0; j < 4; j++)
                    acc[i][j] = fmaf(a[i], bb[j], acc[i][j]);
        }
        __syncthreads();
    }
#pragma unroll
    for (int j = 0; j < 4; j++) {
        int e = bn + tx * 4 + j;
        float bv = bias[e];
        float4 o;
#pragma unroll
        for (int i = 0; i < 4; i++) {
            float v = acc[i][j] + bv;
            v = (v > 20.f) ? v : __logf(1.f + __expf(v));
            (&o.x)[i] = v;
        }
        *(float4*)(outT + (size_t)e * SEQ + bm + ty * 4) = o;
    }
}

// ---------------- fused conv(w=4, causal) + bias + SiLU + transpose -------
__global__ void conv_t(const unsigned short* __restrict__ xi_raw,
                       const float* __restrict__ w, const float* __restrict__ cb,
                       unsigned short* __restrict__ xi2bf, unsigned short* __restrict__ xi2T) {
    __shared__ float tin[67][72];
    __shared__ float tout[64][65];
    int l0 = blockIdx.x * 64, e0 = blockIdx.y * 64;
    int t = threadIdx.x;
    for (int c = t; c < 536; c += 256) {      // 67 rows x 8 chunks of 8
        int r = c >> 3, ke = (c & 7) * 8;
        int l = l0 - 3 + r;
        frag8 v = {0, 0, 0, 0, 0, 0, 0, 0};
        if (l >= 0) v = *(const frag8*)(xi_raw + (size_t)l * DI + e0 + ke);
#pragma unroll
        for (int i = 0; i < 8; i++) tin[r][ke + i] = bf2f((unsigned short)v[i]);
    }
    __syncthreads();
    int e_loc = t & 63;
    int e = e0 + e_loc;
    float4 wv = *(const float4*)(w + e * 4);
    float bias = cb[e];
#pragma unroll 4
    for (int i = 0; i < 16; i++) {
        int l_loc = (t >> 6) + i * 4;
        float acc = bias;
        acc = fmaf(wv.x, tin[l_loc][e_loc], acc);
        acc = fmaf(wv.y, tin[l_loc + 1][e_loc], acc);
        acc = fmaf(wv.z, tin[l_loc + 2][e_loc], acc);
        acc = fmaf(wv.w, tin[l_loc + 3][e_loc], acc);
        float s = acc / (1.f + __expf(-acc));
        tout[l_loc][e_loc] = s;
        xi2bf[(size_t)(l0 + l_loc) * DI + e] = f2bf(s);
    }
    __syncthreads();
    for (int c = t; c < 1024; c += 256) {     // 64 e-rows x 16 l-chunks of 4
        int er = c >> 4, l4 = (c & 15) * 4;
        ushort4 o = { f2bf(tout[l4][er]), f2bf(tout[l4 + 1][er]),
                      f2bf(tout[l4 + 2][er]), f2bf(tout[l4 + 3][er]) };
        *(ushort4*)(xi2T + (size_t)(e0 + er) * SEQ + l0 + l4) = o;
    }
}

// ---------------- Chunked selective scan: 4 states/lane x 4 channels/wave --
// Lane (g=lane>>4, i=lane&15) holds states 4i..4i+3 of channel e0+g.
// NCHUNK=32 (8 waves/SIMD). passA emits per-channel sum_d + fp32 hend; carry
// recomputes P=exp2(Ae2*sum_d) and writes h_in in-place over hend.
__global__ void scan_passA(const float* __restrict__ deltaT, const unsigned short* __restrict__ xi2T,
                           const unsigned short* __restrict__ bci, const float* __restrict__ A_log,
                           float* __restrict__ sumd, float* __restrict__ hend) {
    int wid = blockIdx.x * 4 + (threadIdx.x >> 6);
    int eg = wid & 255;        // channel group (DI/4)
    int c  = wid >> 8;         // chunk 0..NCHUNK-2
    int lane = threadIdx.x & 63;
    int g = lane >> 4;         // channel within group
    int i = lane & 15;         // state quad
    int e = eg * 4 + g;
    int l0 = c * CHUNK;
    float4 al = *(const float4*)(A_log + e * DS + 4 * i);
    float Ae2[4];
#pragma unroll
    for (int k = 0; k < 4; k++) Ae2[k] = -__expf((&al.x)[k]) * LOG2E;
    float h[4] = {0.f, 0.f, 0.f, 0.f};
    float sum_d = 0.f;
    const float4* d4  = (const float4*)(deltaT + (size_t)e * SEQ + l0);
    const ushort4* x4 = (const ushort4*)(xi2T + (size_t)e * SEQ + l0);
    const uint4* bc4  = (const uint4*)((const unsigned*)bci + (size_t)l0 * 64) + i;
    for (int gq = 0; gq < CHUNK / 4; gq++) {
        float4 dd = d4[gq];
        ushort4 xx = x4[gq];
#pragma unroll
        for (int j = 0; j < 4; j++) {
            uint4 bcv = bc4[(4 * gq + j) * 16];
            float dj = (&dd.x)[j];
            float dx = dj * bf2f((&xx.x)[j]);
            sum_d += dj;
#pragma unroll
            for (int k = 0; k < 4; k++) {
                float dA = fexp2(dj * Ae2[k]);
                float Bk = __int_as_float((&bcv.x)[k] << 16);
                h[k] = fmaf(dA, h[k], dx * Bk);
            }
        }
    }
    size_t idx = ((size_t)c * DI + e) * DS + 4 * i;
    float4 hv = {h[0], h[1], h[2], h[3]};
    *(float4*)(hend + idx) = hv;
    if (i == 0) sumd[c * DI + e] = sum_d;
}

// Carry: batched loads (all chunks up front, independent -> one vmcnt drain)
// then register chain; h_in written over hend in-place. Last slot write-only.
__global__ void scan_carry(float* __restrict__ hend, const float* __restrict__ sumd,
                           const float* __restrict__ A_log) {
    int e = blockIdx.x * 4 + (threadIdx.x >> 6);
    int n = threadIdx.x & 63;
    float Ae2 = -__expf(A_log[e * DS + n]) * LOG2E;
    float he[NCHUNK - 1], sd[NCHUNK - 1];
#pragma unroll
    for (int c = 0; c < NCHUNK - 1; c++)
        he[c] = hend[((size_t)c * DI + e) * DS + n];
#pragma unroll
    for (int c = 0; c < NCHUNK - 1; c++)
        sd[c] = sumd[c * DI + e];
    float h = 0.f;
#pragma unroll
    for (int c = 0; c < NCHUNK - 1; c++) {
        float P = fexp2(Ae2 * sd[c]);
        hend[((size_t)c * DI + e) * DS + n] = h;
        h = fmaf(P, h, he[c]);
    }
    hend[((size_t)(NCHUNK - 1) * DI + e) * DS + n] = h;
}

// Pass B: local 4-state fma chain + 4-DPP 16-lane row reduce; lane i==0 of
// each row gates with silu(z) (szT read-only) and stores y directly to
// y_bf [SEQ][DI].
__global__ void scan_passB(const float* __restrict__ deltaT, const unsigned short* __restrict__ xi2T,
                           const unsigned short* __restrict__ bci, const unsigned short* __restrict__ szT,
                           const float* __restrict__ A_log, const float* __restrict__ Dp,
                           const float* __restrict__ hin, unsigned short* __restrict__ y_bf) {
    int wid = blockIdx.x * 4 + (threadIdx.x >> 6);
    int eg = wid & 255;
    int c  = wid >> 8;
    int lane = threadIdx.x & 63;
    int g = lane >> 4;
    int i = lane & 15;
    int e = eg * 4 + g;
    int l0 = c * CHUNK;
    float4 al = *(const float4*)(A_log + e * DS + 4 * i);
    float Ae2[4];
#pragma unroll
    for (int k = 0; k < 4; k++) Ae2[k] = -__expf((&al.x)[k]) * LOG2E;
    float dp = Dp[e];
    float4 hv = *(const float4*)(hin + ((size_t)c * DI + e) * DS + 4 * i);
    float h[4] = {hv.x, hv.y, hv.z, hv.w};
    const float4* d4  = (const float4*)(deltaT + (size_t)e * SEQ + l0);
    const ushort4* x4 = (const ushort4*)(xi2T + (size_t)e * SEQ + l0);
    const ushort4* s4 = (const ushort4*)(szT + (size_t)e * SEQ + l0);
    const uint4* bc4  = (const uint4*)((const unsigned*)bci + (size_t)l0 * 64) + i;
    for (int gq = 0; gq < CHUNK / 4; gq++) {
        float4 dd = d4[gq];
        ushort4 xx = x4[gq], zz = s4[gq];
        ushort4 yv;
#pragma unroll
        for (int j = 0; j < 4; j++) {
            uint4 bcv = bc4[(4 * gq + j) * 16];
            float dj = (&dd.x)[j];
            float xj = bf2f((&xx.x)[j]);
            float dx = dj * xj;
            float Ck[4];
#pragma unroll
            for (int k = 0; k < 4; k++) {
                unsigned w = (&bcv.x)[k];
                float Bk = __int_as_float(w << 16);
                Ck[k] = __int_as_float(w & 0xffff0000u);
                float dA = fexp2(dj * Ae2[k]);
                h[k] = fmaf(dA, h[k], dx * Bk);
            }
            float p = h[0] * Ck[0];
            p = fmaf(h[1], Ck[1], p);
            p = fmaf(h[2], Ck[2], p);
            p = fmaf(h[3], Ck[3], p);
            p = dppadd<0xB1>(p);   // quad_perm swap-1
            p = dppadd<0x4E>(p);   // quad_perm swap-2
            p = dppadd<0x141>(p);  // row_half_mirror
            p = dppadd<0x140>(p);  // row_mirror -> 16-lane row sum (all lanes)
            (&yv.x)[j] = f2bf((p + dp * xj) * bf2f((&zz.x)[j]));
        }
        if (i == 0) {
#pragma unroll
            for (int j = 0; j < 4; j++)
                y_bf[(size_t)(l0 + 4 * gq + j) * DI + e] = (&yv.x)[j];
        }
    }
}

extern "C" void kernel_launch(void* const* d_in, const int* in_sizes, int n_in,
                              void* d_out, int out_size, void* d_ws, size_t ws_size,
                              hipStream_t stream) {
    const float* x      = (const float*)d_in[0];
    const float* ln_g   = (const float*)d_in[1];
    const float* ln_b   = (const float*)d_in[2];
    const float* Win    = (const float*)d_in[3];
    const float* conv_w = (const float*)d_in[4];
    const float* conv_b = (const float*)d_in[5];
    const float* Wx     = (const float*)d_in[6];
    const float* Wdt    = (const float*)d_in[7];
    const float* bdt    = (const float*)d_in[8];
    const float* A_log  = (const float*)d_in[9];
    const float* Dp     = (const float*)d_in[10];
    const float* Wout   = (const float*)d_in[11];
    float* out = (float*)d_out;

    // Workspace map (30.2 MB peak; 31.5 MB proven safe). Lifetimes:
    //  0- 8: xi_raw (2-3) -> deltaT (5-8)
    //  8-12: Win_bf (1-2) -> xi2bf (3-4) -> y_bf (8-9)
    // 12-16: szT (2-8, read-only in passB)
    // 16-20: xi2T (3-8)
    // 20-28: xn_bf (1-2) -> hend/h_in fp32 [NCHUNK][DI][DS] (6-8)
    // 28-29: Wout_bf (1-9)
    // 29+  : sumd 128K | Wx_bf 320K | dtc 256K | bci 512K
    char* W = (char*)d_ws;
    unsigned short* xi_raw  = (unsigned short*)W;
    float*          deltaT  = (float*)W;
    unsigned short* Win_bf  = (unsigned short*)(W + 8 * MB);
    unsigned short* xi2bf   = (unsigned short*)(W + 8 * MB);
    unsigned short* y_bf    = (unsigned short*)(W + 8 * MB);
    unsigned short* szT     = (unsigned short*)(W + 12 * MB);
    unsigned short* xi2T    = (unsigned short*)(W + 16 * MB);
    unsigned short* xn_bf   = (unsigned short*)(W + 20 * MB);
    float*          hend    = (float*)(W + 20 * MB);
    unsigned short* Wout_bf = (unsigned short*)(W + 28 * MB);
    float*          sumd    = (float*)(W + 29 * MB);
    unsigned short* Wx_bf   = (unsigned short*)(W + 29 * MB + 128 * 1024);
    float*          dtc     = (float*)(W + 29 * MB + 448 * 1024);
    unsigned short* bci     = (unsigned short*)(W + 29 * MB + 704 * 1024);

    // 1. fused: weights -> bf16 (Win 1,048,576 / Wx 163,840 / Wout 524,288) + LN
    cvt_ln<<<NCVT + SEQ, 256, 0, stream>>>(Win, Win_bf, Wx, Wx_bf, Wout, Wout_bf,
                                           x, ln_g, ln_b, xn_bf);

    // 2. fused in-proj [2048 x 2048 x 512], 128x64 tile (512 blocks = 2/CU):
    //    lower half -> xi_raw bf16, upper half -> silu -> szT bf16 transposed
    gemm_bf<1><<<dim3(SEQ / 128, 2048 / 64), 256, 0, stream>>>(
        xn_bf, DM, Win_bf, DM, 2048, DM, nullptr, nullptr, 0, nullptr, nullptr,
        xi_raw, szT);

    // 3. fused conv + SiLU + transpose -> xi2bf [SEQ][DI] + xi2T [DI][SEQ]
    conv_t<<<dim3(SEQ / 64, DI / 64), 256, 0, stream>>>(xi_raw, conv_w, conv_b, xi2bf, xi2T);

    // 4. x-proj split epilogue: dtc fp32 [SEQ][32] + bci bf16 interleaved [SEQ][128]
    gemm_bf<4><<<dim3(SEQ / 128, 3), 256, 0, stream>>>(
        xi2bf, DI, Wx_bf, DI, 160, DI, nullptr, nullptr, 0, dtc, bci, nullptr, nullptr);

    // 5. deltaT = softplus(dtc @ Wdt^T + bdt)^T  [DI][SEQ] fp32
    gemm_dt_t<<<dim3(SEQ / 64, DI / 64), 256, 0, stream>>>(dtc, Wdt, bdt, deltaT);

    // 6. chunked scan (4 ch/wave, 32 chunks): A (0..30) -> batched carry -> B
    scan_passA<<<(DI / 4) * (NCHUNK - 1) / 4, 256, 0, stream>>>(deltaT, xi2T, bci, A_log, sumd, hend);
    scan_carry<<<DI / 4, 256, 0, stream>>>(hend, sumd, A_log);
    scan_passB<<<(DI / 4) * NCHUNK / 4, 256, 0, stream>>>(deltaT, xi2T, bci, szT,
                                                          A_log, Dp, hend, y_bf);

    // 7. out = y @ Wout^T + x  fp32  (y_bf written directly by passB)
    gemm_bf<2><<<dim3(SEQ / 128, DM / 64), 256, 0, stream>>>(
        y_bf, DI, Wout_bf, DI, DM, DI, out, x, DM, nullptr, nullptr, nullptr, nullptr);
}